// Round 16
// baseline (4555.120 us; speedup 1.0000x reference)
//
#include <hip/hip_runtime.h>

typedef unsigned int u32;
typedef unsigned short u16;
typedef unsigned long long u64;
typedef __attribute__((ext_vector_type(2))) _Float16 h2v;
typedef __attribute__((ext_vector_type(4))) _Float16 f16x4;
typedef __attribute__((ext_vector_type(4))) float f32x4;

#define BB 32
#define TT 2048
#define CC 256
#define ESZ 256
#define GG 1024   // 4*es
#define NG 8      // sibling blocks per batch (8*32 = 256 blocks = all CUs)
#define NW 128    // h2 words per batch

// ---------------- helpers ----------------
__device__ __forceinline__ float fdot2u(u32 a, u32 b, float c) {
#if __has_builtin(__builtin_amdgcn_fdot2)
  return __builtin_amdgcn_fdot2(__builtin_bit_cast(h2v, a), __builtin_bit_cast(h2v, b), c, false);
#else
  h2v av = __builtin_bit_cast(h2v, a), bv = __builtin_bit_cast(h2v, b);
  return c + (float)av[0] * (float)bv[0] + (float)av[1] * (float)bv[1];
#endif
}

__device__ __forceinline__ float sigm_f(float x) {
  float e = __builtin_amdgcn_exp2f(x * -1.442695041f);
  return __builtin_amdgcn_rcpf(1.0f + e);
}
__device__ __forceinline__ float tanh_f(float x) {
  float e = __builtin_amdgcn_exp2f(x * 2.885390082f);  // exp(2x)
  return 1.0f - 2.0f * __builtin_amdgcn_rcpf(e + 1.0f);
}

// L2-tier (same-XCD) communication: sc0 = bypass L1, stay in L2.
__device__ __forceinline__ u64 ld_l2(const u64* p) {
  u64 v;
  asm volatile("global_load_dwordx2 %0, %1, off sc0\n\ts_waitcnt vmcnt(0)"
               : "=v"(v) : "v"(p) : "memory");
  return v;
}
__device__ __forceinline__ void st_l2(u64* p, u64 v) {
  asm volatile("global_store_dwordx2 %0, %1, off sc0" :: "v"(p), "v"(v) : "memory");
}

// ---------------- kernel 0a: pack W2 (f32 [256][1024] -> h2 rows [128][1024]) ----------------
__global__ void k_pack_w2(const float* __restrict__ W2, u32* __restrict__ W2p) {
  int gid = blockIdx.x * 256 + threadIdx.x;   // m = gid>>10, j = gid&1023
  int m = gid >> 10, j = gid & 1023;
  _Float16 lo = (_Float16)W2[(size_t)(2 * m) * GG + j];
  _Float16 hi = (_Float16)W2[(size_t)(2 * m + 1) * GG + j];
  W2p[gid] = (u32)__builtin_bit_cast(u16, lo) | ((u32)__builtin_bit_cast(u16, hi) << 16);
}

// ---------------- kernel 0b: init BOTH slab copies (slot0 = tag0 + h0; slot1 = 0) ----------------
__global__ void k_init_slab(const float* __restrict__ h0, u64* __restrict__ slab,
                            u64* __restrict__ slabL2) {
  int idx = blockIdx.x * 256 + threadIdx.x;   // 0..8191
  int slot = idx >> 12;                       // 4096 words per slot
  int rem = idx & 4095;
  int b = rem >> 7, r = rem & 127;
  u64 word = 0;
  if (slot == 0) {
    _Float16 lo = (_Float16)h0[b * ESZ + 2 * r];
    _Float16 hi = (_Float16)h0[b * ESZ + 2 * r + 1];
    u32 h2 = (u32)__builtin_bit_cast(u16, lo) | ((u32)__builtin_bit_cast(u16, hi) << 16);
    word = ((u64)h2 << 32);                   // tag = 0
  }
  size_t off = (size_t)slot * (BB * NW) + b * NW + r;
  slab[off] = word;
  slabL2[off] = word;
}

// ---------------- kernel 1: pre = x@W1 + b1 + b2  (f16 MFMA, out f16 [B*T][1024]) ----------------
__global__ __launch_bounds__(256, 2) void k_pre_gemm(
    const float* __restrict__ x, const float* __restrict__ W1,
    const float* __restrict__ b1, const float* __restrict__ b2,
    _Float16* __restrict__ pre) {
  __shared__ __attribute__((aligned(16))) _Float16 Al[128 * 36];
  __shared__ __attribute__((aligned(16))) _Float16 Bl[64 * 36];
  const int tid = threadIdx.x;
  const int lane = tid & 63, wv = tid >> 6;
  const int wr = wv >> 1, wc = wv & 1;
  const int rowBase = blockIdx.x * 128;
  const int colBase = blockIdx.y * 64;

  f32x4 acc[4][2];
#pragma unroll
  for (int mi = 0; mi < 4; ++mi)
#pragma unroll
    for (int ni = 0; ni < 2; ++ni) acc[mi][ni] = (f32x4){0.f, 0.f, 0.f, 0.f};

  for (int k0 = 0; k0 < 256; k0 += 32) {
#pragma unroll
    for (int i = 0; i < 4; ++i) {
      int fidx = tid + 256 * i;
      int row = fidx >> 3, kc = (fidx & 7) * 4;
      const float4 v = *(const float4*)(x + (size_t)(rowBase + row) * 256 + k0 + kc);
      f16x4 hv = { (_Float16)v.x, (_Float16)v.y, (_Float16)v.z, (_Float16)v.w };
      *(f16x4*)&Al[row * 36 + kc] = hv;
    }
#pragma unroll
    for (int i = 0; i < 8; ++i) {
      int idx = tid + 256 * i;
      int k = idx >> 6, n = idx & 63;
      Bl[n * 36 + k] = (_Float16)W1[(size_t)(k0 + k) * GG + colBase + n];
    }
    __syncthreads();

#pragma unroll
    for (int kk = 0; kk < 2; ++kk) {
      int ka = (lane >> 4) * 4 + kk * 16;
      f16x4 af[4], bf[2];
#pragma unroll
      for (int mi = 0; mi < 4; ++mi)
        af[mi] = *(const f16x4*)&Al[(wr * 64 + mi * 16 + (lane & 15)) * 36 + ka];
#pragma unroll
      for (int ni = 0; ni < 2; ++ni)
        bf[ni] = *(const f16x4*)&Bl[(wc * 32 + ni * 16 + (lane & 15)) * 36 + ka];
#pragma unroll
      for (int mi = 0; mi < 4; ++mi)
#pragma unroll
        for (int ni = 0; ni < 2; ++ni)
          acc[mi][ni] = __builtin_amdgcn_mfma_f32_16x16x16f16(af[mi], bf[ni], acc[mi][ni], 0, 0, 0);
    }
    __syncthreads();
  }

#pragma unroll
  for (int ni = 0; ni < 2; ++ni) {
    int col = colBase + wc * 32 + ni * 16 + (lane & 15);
    float bias = b1[col] + b2[col];
#pragma unroll
    for (int mi = 0; mi < 4; ++mi) {
      int r0 = rowBase + wr * 64 + mi * 16 + (lane >> 4) * 4;
#pragma unroll
      for (int rr = 0; rr < 4; ++rr)
        pre[(size_t)(r0 + rr) * GG + col] = (_Float16)(acc[mi][ni][rr] + bias);
    }
  }
}

// ---------------- kernel 2: the recurrence, 8 CUs per batch ----------------
// r14 structure (AGPR weights) + DUAL-COPY h exchange:
//  - publish: plain sc0 store (writer-XCD L2 copy) THEN agent-atomic (LLC copy)
//  - poll: sc0 L2 loads (fast iff siblings same-XCD; bid=g*32+b => all
//    siblings == b mod 8 -> same XCD under round-robin) with periodic
//    agent-atomic fallback -> placement-independent correctness (G16).
// Overwrite-safety: per-block publish@s follows its reads@s-1 in program
// order; a writer only reaches step s after ALL blocks published tag s
// (its own poll@s saw every word) => all reads@s-1 done. Holds per copy.
__global__ __launch_bounds__(256, 1)
__attribute__((amdgpu_waves_per_eu(1, 1)))
void k_lstm_rec(
    const _Float16* __restrict__ pre, const u32* __restrict__ W2p,
    const float* __restrict__ c0, u64* __restrict__ slab, u64* __restrict__ slabL2,
    float* __restrict__ out1, float* __restrict__ out2,
    float* __restrict__ hN, float* __restrict__ cN) {
  __shared__ float part[2][4][64];   // [parity][wave][lane] h1->h0 partials

  const int bid = blockIdx.x;
  const int b = bid & 31;        // batch
  const int g = bid >> 5;        // sibling 0..7
  const int t = threadIdx.x;
  const int l = t & 63;          // lane
  const int w = t >> 6;          // wave 0..3
  const int half = w & 1;        // k-half (wave-uniform!)
  const int set = w >> 1;        // es sub-block 0..1
  const int es_l = l & 15;
  const int gate = l >> 4;       // 0:f 1:i 2:o 3:ch
  const int E0 = 32 * g + 16 * set;
  const int j = E0 + es_l;               // es index
  const int col = j + 256 * gate;        // gate column

  // 64 weight h2-rows for this column -> AGPR storage (opaque, un-remat-able)
  u32 wa[64];
#pragma unroll
  for (int m = 0; m < 64; ++m) {
    u32 tmp = W2p[(64 * half + m) * GG + col];
    asm("v_accvgpr_write_b32 %0, %1" : "=a"(wa[m]) : "v"(tmp));
  }

  float creg = 0.f, hlast = 0.f;
  if (!half) creg = c0[b * ESZ + j];

  const _Float16* preB = pre + (size_t)b * TT * GG;
  _Float16 q = (_Float16)0.f;
  if (!half) q = preB[col];      // only h0 carries pre

  for (int s = 0; s < TT; ++s) {
    // ---- tiered poll of own word: word 64*half + l, tag == s ----
    const size_t off = (size_t)(s & 1) * (BB * NW) + b * NW + 64 * half + l;
    const u64* pf = slabL2 + off;      // L2 copy (fast, heuristic)
    const u64* pa = slab + off;        // LLC copy (always coherent)
    const u32 want = (u32)s;

    u64 wv_ = ld_l2(pf);
    int spin = 0;
    while ((u32)wv_ != want) {
      if (++spin >= 4) {
        u64 av = __hip_atomic_load(pa, __ATOMIC_RELAXED, __HIP_MEMORY_SCOPE_AGENT);
        if ((u32)av == want) { wv_ = av; break; }
        spin = 0;
      }
      wv_ = ld_l2(pf);
    }
    u32 hv_ = (u32)(wv_ >> 32);  // h2 row 64*half + l

    // ---- 64-row dot: avread + uniform-src readlane + dot2, 2 chains ----
    float A0 = 0.f, A1 = 0.f;
#pragma unroll
    for (int k = 0; k < 32; ++k) {
      u32 w0_, w1_;
      asm("v_accvgpr_read_b32 %0, %1" : "=v"(w0_) : "a"(wa[2 * k]));
      asm("v_accvgpr_read_b32 %0, %1" : "=v"(w1_) : "a"(wa[2 * k + 1]));
      u32 hm0 = (u32)__builtin_amdgcn_readlane((int)hv_, 2 * k);
      u32 hm1 = (u32)__builtin_amdgcn_readlane((int)hv_, 2 * k + 1);
      A0 = fdot2u(hm0, w0_, A0);
      A1 = fdot2u(hm1, w1_, A1);
    }
    float A = A0 + A1;

    float qf = 0.f;
    if (!half) {
      qf = (float)q;
      if (s + 1 < TT) q = preB[(size_t)(s + 1) * GG + col];  // prefetch
    } else {
      part[s & 1][w][l] = A;     // hand partial to the h0 partner wave
    }

    asm volatile("s_waitcnt lgkmcnt(0)" ::: "memory");
    __builtin_amdgcn_s_barrier();

    if (!half) {                 // wave-uniform branch: h1 waves skip entirely
      float v = A + qf + part[s & 1][w | 1][l];
      float gv = (gate == 3) ? tanh_f(v) : sigm_f(v);

      float fg = __shfl(gv, es_l);
      float ig = __shfl(gv, es_l + 16);
      float og = __shfl(gv, es_l + 32);
      float ch = __shfl(gv, es_l + 48);
      creg = fg * creg + ig * ch;
      float hv = og * tanh_f(creg);
      hlast = hv;

      // publish tagged word (es pair) into the other parity slot — both copies
      float hp = __shfl_xor(hv, 1);
      if (l < 16 && (l & 1) == 0) {
        _Float16 lo16 = (_Float16)hv, hi16 = (_Float16)hp;
        u32 h2p = (u32)__builtin_bit_cast(u16, lo16) | ((u32)__builtin_bit_cast(u16, hi16) << 16);
        u64 word = ((u64)h2p << 32) | (u32)(s + 1);
        size_t oo = (size_t)((s + 1) & 1) * (BB * NW) + b * NW + ((E0 + l) >> 1);
        st_l2(slabL2 + oo, word);   // fast L2 copy first
        __hip_atomic_store(slab + oo, word, __ATOMIC_RELAXED, __HIP_MEMORY_SCOPE_AGENT);
      }
      if (l < 16) {
        out1[(size_t)b * TT * ESZ + (size_t)s * ESZ + j] = hv;   // [B, T*es]
        out2[(size_t)s * (BB * ESZ) + b * ESZ + j] = hv;         // [T, B, es]
      }
    }
  }

  if (!half && l < 16) {
    hN[b * ESZ + j] = hlast;
    cN[b * ESZ + j] = creg;
  }
}

// ---------------- launch ----------------
extern "C" void kernel_launch(void* const* d_in, const int* in_sizes, int n_in,
                              void* d_out, int out_size, void* d_ws, size_t ws_size,
                              hipStream_t stream) {
  const float* x  = (const float*)d_in[0];
  const float* h0 = (const float*)d_in[1];
  const float* c0 = (const float*)d_in[2];
  const float* W1 = (const float*)d_in[3];
  const float* W2 = (const float*)d_in[4];
  const float* b1 = (const float*)d_in[5];
  const float* b2 = (const float*)d_in[6];

  float* out1 = (float*)d_out;
  float* out2 = out1 + (size_t)BB * TT * ESZ;
  float* hN   = out2 + (size_t)BB * TT * ESZ;
  float* cN   = hN + BB * ESZ;

  _Float16* pre = (_Float16*)d_ws;                                  // 128 MB
  u32* W2p = (u32*)((char*)d_ws + (size_t)BB * TT * GG * 2);        // 512 KB
  u64* slab = (u64*)((char*)W2p + 128 * GG * 4);                    // 64 KB (LLC copy)
  u64* slabL2 = slab + 2 * BB * NW;                                 // 64 KB (L2 copy)

  k_pack_w2<<<512, 256, 0, stream>>>(W2, W2p);
  k_init_slab<<<32, 256, 0, stream>>>(h0, slab, slabL2);
  k_pre_gemm<<<dim3(512, 16), 256, 0, stream>>>(x, W1, b1, b2, pre);

  k_lstm_rec<<<NG * BB, 256, 0, stream>>>(pre, W2p, c0, slab, slabL2, out1, out2, hN, cN);
}

// Round 19
// 3699.853 us; speedup vs baseline: 1.2312x; 1.2312x over previous
//
#include <hip/hip_runtime.h>

typedef unsigned int u32;
typedef unsigned short u16;
typedef unsigned long long u64;
typedef __attribute__((ext_vector_type(2))) _Float16 h2v;
typedef __attribute__((ext_vector_type(4))) _Float16 f16x4;
typedef __attribute__((ext_vector_type(4))) float f32x4;

#define BB 32
#define TT 2048
#define CC 256
#define ESZ 256
#define GG 1024   // 4*es
#define NG 8      // sibling blocks per batch (8*32 = 256 blocks = all CUs)
#define NW 128    // h2 words per batch

// ---------------- helpers ----------------
__device__ __forceinline__ float fdot2u(u32 a, u32 b, float c) {
#if __has_builtin(__builtin_amdgcn_fdot2)
  return __builtin_amdgcn_fdot2(__builtin_bit_cast(h2v, a), __builtin_bit_cast(h2v, b), c, false);
#else
  h2v av = __builtin_bit_cast(h2v, a), bv = __builtin_bit_cast(h2v, b);
  return c + (float)av[0] * (float)bv[0] + (float)av[1] * (float)bv[1];
#endif
}

__device__ __forceinline__ float sigm_f(float x) {
  float e = __builtin_amdgcn_exp2f(x * -1.442695041f);
  return __builtin_amdgcn_rcpf(1.0f + e);
}
__device__ __forceinline__ float tanh_f(float x) {
  float e = __builtin_amdgcn_exp2f(x * 2.885390082f);  // exp(2x)
  return 1.0f - 2.0f * __builtin_amdgcn_rcpf(e + 1.0f);
}

// ---------------- kernel 0a: pack W2 (f32 [256][1024] -> h2 rows [128][1024]) ----------------
__global__ void k_pack_w2(const float* __restrict__ W2, u32* __restrict__ W2p) {
  int gid = blockIdx.x * 256 + threadIdx.x;   // m = gid>>10, j = gid&1023
  int m = gid >> 10, j = gid & 1023;
  _Float16 lo = (_Float16)W2[(size_t)(2 * m) * GG + j];
  _Float16 hi = (_Float16)W2[(size_t)(2 * m + 1) * GG + j];
  W2p[gid] = (u32)__builtin_bit_cast(u16, lo) | ((u32)__builtin_bit_cast(u16, hi) << 16);
}

// ---------------- kernel 0b: init exchange slab (slot0 = tag0 + h0; slot1 = 0) ----------------
__global__ void k_init_slab(const float* __restrict__ h0, u64* __restrict__ slab) {
  int idx = blockIdx.x * 256 + threadIdx.x;   // 0..8191
  int slot = idx >> 12;                       // 4096 words per slot
  int rem = idx & 4095;
  int b = rem >> 7, r = rem & 127;
  u64 word = 0;
  if (slot == 0) {
    _Float16 lo = (_Float16)h0[b * ESZ + 2 * r];
    _Float16 hi = (_Float16)h0[b * ESZ + 2 * r + 1];
    u32 h2 = (u32)__builtin_bit_cast(u16, lo) | ((u32)__builtin_bit_cast(u16, hi) << 16);
    word = ((u64)h2 << 32);                   // tag = 0
  }
  slab[(size_t)slot * (BB * NW) + b * NW + r] = word;
}

// ---------------- kernel 1: pre = x@W1 + b1 + b2  (f16 MFMA, out f16 [B*T][1024]) ----------------
__global__ __launch_bounds__(256, 2) void k_pre_gemm(
    const float* __restrict__ x, const float* __restrict__ W1,
    const float* __restrict__ b1, const float* __restrict__ b2,
    _Float16* __restrict__ pre) {
  __shared__ __attribute__((aligned(16))) _Float16 Al[128 * 36];
  __shared__ __attribute__((aligned(16))) _Float16 Bl[64 * 36];
  const int tid = threadIdx.x;
  const int lane = tid & 63, wv = tid >> 6;
  const int wr = wv >> 1, wc = wv & 1;
  const int rowBase = blockIdx.x * 128;
  const int colBase = blockIdx.y * 64;

  f32x4 acc[4][2];
#pragma unroll
  for (int mi = 0; mi < 4; ++mi)
#pragma unroll
    for (int ni = 0; ni < 2; ++ni) acc[mi][ni] = (f32x4){0.f, 0.f, 0.f, 0.f};

  for (int k0 = 0; k0 < 256; k0 += 32) {
#pragma unroll
    for (int i = 0; i < 4; ++i) {
      int fidx = tid + 256 * i;
      int row = fidx >> 3, kc = (fidx & 7) * 4;
      const float4 v = *(const float4*)(x + (size_t)(rowBase + row) * 256 + k0 + kc);
      f16x4 hv = { (_Float16)v.x, (_Float16)v.y, (_Float16)v.z, (_Float16)v.w };
      *(f16x4*)&Al[row * 36 + kc] = hv;
    }
#pragma unroll
    for (int i = 0; i < 8; ++i) {
      int idx = tid + 256 * i;
      int k = idx >> 6, n = idx & 63;
      Bl[n * 36 + k] = (_Float16)W1[(size_t)(k0 + k) * GG + colBase + n];
    }
    __syncthreads();

#pragma unroll
    for (int kk = 0; kk < 2; ++kk) {
      int ka = (lane >> 4) * 4 + kk * 16;
      f16x4 af[4], bf[2];
#pragma unroll
      for (int mi = 0; mi < 4; ++mi)
        af[mi] = *(const f16x4*)&Al[(wr * 64 + mi * 16 + (lane & 15)) * 36 + ka];
#pragma unroll
      for (int ni = 0; ni < 2; ++ni)
        bf[ni] = *(const f16x4*)&Bl[(wc * 32 + ni * 16 + (lane & 15)) * 36 + ka];
#pragma unroll
      for (int mi = 0; mi < 4; ++mi)
#pragma unroll
        for (int ni = 0; ni < 2; ++ni)
          acc[mi][ni] = __builtin_amdgcn_mfma_f32_16x16x16f16(af[mi], bf[ni], acc[mi][ni], 0, 0, 0);
    }
    __syncthreads();
  }

#pragma unroll
  for (int ni = 0; ni < 2; ++ni) {
    int col = colBase + wc * 32 + ni * 16 + (lane & 15);
    float bias = b1[col] + b2[col];
#pragma unroll
    for (int mi = 0; mi < 4; ++mi) {
      int r0 = rowBase + wr * 64 + mi * 16 + (lane >> 4) * 4;
#pragma unroll
      for (int rr = 0; rr < 4; ++rr)
        pre[(size_t)(r0 + rr) * GG + col] = (_Float16)(acc[mi][ni][rr] + bias);
    }
  }
}

// ---------------- kernel 2: the recurrence, 8 CUs per batch ----------------
// EXACT r13 structure (fastest passing: 3.15ms) with ONE change: the poll
// loop is wave-uniform (all 64 lanes re-load every iteration, exit together
// via ballot). Divergent-exit spin left lanes issuing per-lane atomic loads
// to 64 different addresses -> serialized LLC transactions (~2000 cyc/iter).
// Uniform mask over 64 consecutive u64 = coalesced 512B request (~1 RTT).
__global__ __launch_bounds__(256, 1)
__attribute__((amdgpu_waves_per_eu(1, 1)))
void k_lstm_rec(
    const _Float16* __restrict__ pre, const u32* __restrict__ W2p,
    const float* __restrict__ c0, u64* __restrict__ slab,
    float* __restrict__ out1, float* __restrict__ out2,
    float* __restrict__ hN, float* __restrict__ cN) {
  __shared__ float part[2][4][64];   // [parity][wave][lane] h1->h0 partials

  const int bid = blockIdx.x;
  const int b = bid & 31;        // batch
  const int g = bid >> 5;        // sibling 0..7
  const int t = threadIdx.x;
  const int l = t & 63;          // lane
  const int w = t >> 6;          // wave 0..3
  const int half = w & 1;        // k-half (wave-uniform!)
  const int set = w >> 1;        // es sub-block 0..1
  const int es_l = l & 15;
  const int gate = l >> 4;       // 0:f 1:i 2:o 3:ch
  const int E0 = 32 * g + 16 * set;
  const int j = E0 + es_l;               // es index
  const int col = j + 256 * gate;        // gate column

  // 64 weight h2-rows for this column, rows [64*half, 64*half+64)
  u32 wreg[64];
#pragma unroll
  for (int m = 0; m < 64; ++m) wreg[m] = W2p[(64 * half + m) * GG + col];
#pragma unroll
  for (int m = 0; m < 64; ++m) asm volatile("" : "+v"(wreg[m]));

  float creg = 0.f, hlast = 0.f;
  if (!half) creg = c0[b * ESZ + j];

  const _Float16* preB = pre + (size_t)b * TT * GG;
  _Float16 q = (_Float16)0.f;
  if (!half) q = preB[col];      // only h0 carries pre

  for (int s = 0; s < TT; ++s) {
    // ---- wave-uniform coalesced poll: word 64*half + l, tag == s ----
    u64* basep = slab + (size_t)(s & 1) * (BB * NW) + b * NW + 64 * half;
    const u32 want = (u32)s;
    u64 wv_ = 0;
    u32 got = 0;
    do {
      u64 tmp = __hip_atomic_load(&basep[l], __ATOMIC_RELAXED, __HIP_MEMORY_SCOPE_AGENT);
      if (!got && (u32)tmp == want) { wv_ = tmp; got = 1; }
    } while (__ballot(got == 0));   // all 64 lanes load each iter -> coalesced
    u32 hv_ = (u32)(wv_ >> 32);  // h2 row 64*half + l

    // ---- 64-row dot: uniform-src readlane + dot2, 2 chains ----
    float A0 = 0.f, A1 = 0.f;
#pragma unroll
    for (int k = 0; k < 32; ++k) {
      u32 hm0 = (u32)__builtin_amdgcn_readlane((int)hv_, 2 * k);
      u32 hm1 = (u32)__builtin_amdgcn_readlane((int)hv_, 2 * k + 1);
      A0 = fdot2u(hm0, wreg[2 * k], A0);
      A1 = fdot2u(hm1, wreg[2 * k + 1], A1);
    }
    float A = A0 + A1;

    float qf = 0.f;
    if (!half) {
      qf = (float)q;
      if (s + 1 < TT) q = preB[(size_t)(s + 1) * GG + col];  // prefetch
    } else {
      part[s & 1][w][l] = A;     // hand partial to the h0 partner wave
    }

    asm volatile("s_waitcnt lgkmcnt(0)" ::: "memory");
    __builtin_amdgcn_s_barrier();

    if (!half) {                 // wave-uniform branch: h1 waves skip entirely
      float v = A + qf + part[s & 1][w | 1][l];
      float gv = (gate == 3) ? tanh_f(v) : sigm_f(v);

      float fg = __shfl(gv, es_l);
      float ig = __shfl(gv, es_l + 16);
      float og = __shfl(gv, es_l + 32);
      float ch = __shfl(gv, es_l + 48);
      creg = fg * creg + ig * ch;
      float hv = og * tanh_f(creg);
      hlast = hv;

      // publish tagged word (es pair) into the other parity slot
      float hp = __shfl_xor(hv, 1);
      if (l < 16 && (l & 1) == 0) {
        _Float16 lo16 = (_Float16)hv, hi16 = (_Float16)hp;
        u32 h2p = (u32)__builtin_bit_cast(u16, lo16) | ((u32)__builtin_bit_cast(u16, hi16) << 16);
        u64 word = ((u64)h2p << 32) | (u32)(s + 1);
        int r = (E0 + l) >> 1;
        u64* outp = slab + (size_t)((s + 1) & 1) * (BB * NW) + b * NW + r;
        __hip_atomic_store(outp, word, __ATOMIC_RELAXED, __HIP_MEMORY_SCOPE_AGENT);
      }
      if (l < 16) {
        out1[(size_t)b * TT * ESZ + (size_t)s * ESZ + j] = hv;   // [B, T*es]
        out2[(size_t)s * (BB * ESZ) + b * ESZ + j] = hv;         // [T, B, es]
      }
    }
  }

  if (!half && l < 16) {
    hN[b * ESZ + j] = hlast;
    cN[b * ESZ + j] = creg;
  }
}

// ---------------- launch ----------------
extern "C" void kernel_launch(void* const* d_in, const int* in_sizes, int n_in,
                              void* d_out, int out_size, void* d_ws, size_t ws_size,
                              hipStream_t stream) {
  const float* x  = (const float*)d_in[0];
  const float* h0 = (const float*)d_in[1];
  const float* c0 = (const float*)d_in[2];
  const float* W1 = (const float*)d_in[3];
  const float* W2 = (const float*)d_in[4];
  const float* b1 = (const float*)d_in[5];
  const float* b2 = (const float*)d_in[6];

  float* out1 = (float*)d_out;
  float* out2 = out1 + (size_t)BB * TT * ESZ;
  float* hN   = out2 + (size_t)BB * TT * ESZ;
  float* cN   = hN + BB * ESZ;

  _Float16* pre = (_Float16*)d_ws;                                  // 128 MB
  u32* W2p = (u32*)((char*)d_ws + (size_t)BB * TT * GG * 2);        // 512 KB
  u64* slab = (u64*)((char*)W2p + 128 * GG * 4);                    // 64 KB

  k_pack_w2<<<512, 256, 0, stream>>>(W2, W2p);
  k_init_slab<<<32, 256, 0, stream>>>(h0, slab);
  k_pre_gemm<<<dim3(512, 16), 256, 0, stream>>>(x, W1, b1, b2, pre);

  k_lstm_rec<<<NG * BB, 256, 0, stream>>>(pre, W2p, c0, slab, out1, out2, hN, cN);
}

// Round 21
// 3143.665 us; speedup vs baseline: 1.4490x; 1.1769x over previous
//
#include <hip/hip_runtime.h>

typedef unsigned int u32;
typedef unsigned short u16;
typedef unsigned long long u64;
typedef __attribute__((ext_vector_type(2))) _Float16 h2v;
typedef __attribute__((ext_vector_type(4))) _Float16 f16x4;
typedef __attribute__((ext_vector_type(4))) float f32x4;

#define BB 32
#define TT 2048
#define CC 256
#define ESZ 256
#define GG 1024   // 4*es
#define NG 8      // sibling blocks per batch (8*32 = 256 blocks = all CUs)
#define NW 128    // h2 words per batch

// ---------------- helpers ----------------
__device__ __forceinline__ float fdot2u(u32 a, u32 b, float c) {
#if __has_builtin(__builtin_amdgcn_fdot2)
  return __builtin_amdgcn_fdot2(__builtin_bit_cast(h2v, a), __builtin_bit_cast(h2v, b), c, false);
#else
  h2v av = __builtin_bit_cast(h2v, a), bv = __builtin_bit_cast(h2v, b);
  return c + (float)av[0] * (float)bv[0] + (float)av[1] * (float)bv[1];
#endif
}

__device__ __forceinline__ float sigm_f(float x) {
  float e = __builtin_amdgcn_exp2f(x * -1.442695041f);
  return __builtin_amdgcn_rcpf(1.0f + e);
}
__device__ __forceinline__ float tanh_f(float x) {
  float e = __builtin_amdgcn_exp2f(x * 2.885390082f);  // exp(2x)
  return 1.0f - 2.0f * __builtin_amdgcn_rcpf(e + 1.0f);
}

// ---------------- kernel 0a: pack W2 (f32 [256][1024] -> h2 rows [128][1024]) ----------------
__global__ void k_pack_w2(const float* __restrict__ W2, u32* __restrict__ W2p) {
  int gid = blockIdx.x * 256 + threadIdx.x;   // m = gid>>10, j = gid&1023
  int m = gid >> 10, j = gid & 1023;
  _Float16 lo = (_Float16)W2[(size_t)(2 * m) * GG + j];
  _Float16 hi = (_Float16)W2[(size_t)(2 * m + 1) * GG + j];
  W2p[gid] = (u32)__builtin_bit_cast(u16, lo) | ((u32)__builtin_bit_cast(u16, hi) << 16);
}

// ---------------- kernel 0b: init exchange slab (slot0 = tag0 + h0; slot1 = 0) ----------------
__global__ void k_init_slab(const float* __restrict__ h0, u64* __restrict__ slab) {
  int idx = blockIdx.x * 256 + threadIdx.x;   // 0..8191
  int slot = idx >> 12;                       // 4096 words per slot
  int rem = idx & 4095;
  int b = rem >> 7, r = rem & 127;
  u64 word = 0;
  if (slot == 0) {
    _Float16 lo = (_Float16)h0[b * ESZ + 2 * r];
    _Float16 hi = (_Float16)h0[b * ESZ + 2 * r + 1];
    u32 h2 = (u32)__builtin_bit_cast(u16, lo) | ((u32)__builtin_bit_cast(u16, hi) << 16);
    word = ((u64)h2 << 32);                   // tag = 0
  }
  slab[(size_t)slot * (BB * NW) + b * NW + r] = word;
}

// ---------------- kernel 1: pre = x@W1 + b1 + b2  (f16 MFMA, out f16 [B*T][1024]) ----------------
__global__ __launch_bounds__(256, 2) void k_pre_gemm(
    const float* __restrict__ x, const float* __restrict__ W1,
    const float* __restrict__ b1, const float* __restrict__ b2,
    _Float16* __restrict__ pre) {
  __shared__ __attribute__((aligned(16))) _Float16 Al[128 * 36];
  __shared__ __attribute__((aligned(16))) _Float16 Bl[64 * 36];
  const int tid = threadIdx.x;
  const int lane = tid & 63, wv = tid >> 6;
  const int wr = wv >> 1, wc = wv & 1;
  const int rowBase = blockIdx.x * 128;
  const int colBase = blockIdx.y * 64;

  f32x4 acc[4][2];
#pragma unroll
  for (int mi = 0; mi < 4; ++mi)
#pragma unroll
    for (int ni = 0; ni < 2; ++ni) acc[mi][ni] = (f32x4){0.f, 0.f, 0.f, 0.f};

  for (int k0 = 0; k0 < 256; k0 += 32) {
#pragma unroll
    for (int i = 0; i < 4; ++i) {
      int fidx = tid + 256 * i;
      int row = fidx >> 3, kc = (fidx & 7) * 4;
      const float4 v = *(const float4*)(x + (size_t)(rowBase + row) * 256 + k0 + kc);
      f16x4 hv = { (_Float16)v.x, (_Float16)v.y, (_Float16)v.z, (_Float16)v.w };
      *(f16x4*)&Al[row * 36 + kc] = hv;
    }
#pragma unroll
    for (int i = 0; i < 8; ++i) {
      int idx = tid + 256 * i;
      int k = idx >> 6, n = idx & 63;
      Bl[n * 36 + k] = (_Float16)W1[(size_t)(k0 + k) * GG + colBase + n];
    }
    __syncthreads();

#pragma unroll
    for (int kk = 0; kk < 2; ++kk) {
      int ka = (lane >> 4) * 4 + kk * 16;
      f16x4 af[4], bf[2];
#pragma unroll
      for (int mi = 0; mi < 4; ++mi)
        af[mi] = *(const f16x4*)&Al[(wr * 64 + mi * 16 + (lane & 15)) * 36 + ka];
#pragma unroll
      for (int ni = 0; ni < 2; ++ni)
        bf[ni] = *(const f16x4*)&Bl[(wc * 32 + ni * 16 + (lane & 15)) * 36 + ka];
#pragma unroll
      for (int mi = 0; mi < 4; ++mi)
#pragma unroll
        for (int ni = 0; ni < 2; ++ni)
          acc[mi][ni] = __builtin_amdgcn_mfma_f32_16x16x16f16(af[mi], bf[ni], acc[mi][ni], 0, 0, 0);
    }
    __syncthreads();
  }

#pragma unroll
  for (int ni = 0; ni < 2; ++ni) {
    int col = colBase + wc * 32 + ni * 16 + (lane & 15);
    float bias = b1[col] + b2[col];
#pragma unroll
    for (int mi = 0; mi < 4; ++mi) {
      int r0 = rowBase + wr * 64 + mi * 16 + (lane >> 4) * 4;
#pragma unroll
      for (int rr = 0; rr < 4; ++rr)
        pre[(size_t)(r0 + rr) * GG + col] = (_Float16)(acc[mi][ni][rr] + bias);
    }
  }
}

// ---------------- kernel 2: the recurrence, 8 CUs per batch ----------------
// r13 verbatim — the session's fastest passing kernel (3.15 ms). Cross-CU h
// exchange via tagged u64 words in a parity-double-buffered LLC slab (agent
// atomics). Wall = store->visibility RTT ~1.5us/step; all protocol variants
// (L2 dual-copy, ballot poll, AGPR weights, NG=4) regressed. MFMA branch
// abandoned after 3 failed correctness attempts (absmax ~0.15, codegen-dep).
__global__ __launch_bounds__(256, 1)
__attribute__((amdgpu_waves_per_eu(1, 1)))
void k_lstm_rec(
    const _Float16* __restrict__ pre, const u32* __restrict__ W2p,
    const float* __restrict__ c0, u64* __restrict__ slab,
    float* __restrict__ out1, float* __restrict__ out2,
    float* __restrict__ hN, float* __restrict__ cN) {
  __shared__ float part[2][4][64];   // [parity][wave][lane] h1->h0 partials

  const int bid = blockIdx.x;
  const int b = bid & 31;        // batch
  const int g = bid >> 5;        // sibling 0..7
  const int t = threadIdx.x;
  const int l = t & 63;          // lane
  const int w = t >> 6;          // wave 0..3
  const int half = w & 1;        // k-half (wave-uniform!)
  const int set = w >> 1;        // es sub-block 0..1
  const int es_l = l & 15;
  const int gate = l >> 4;       // 0:f 1:i 2:o 3:ch
  const int E0 = 32 * g + 16 * set;
  const int j = E0 + es_l;               // es index
  const int col = j + 256 * gate;        // gate column

  // 64 weight h2-rows for this column, rows [64*half, 64*half+64) — pinned ONCE
  u32 wreg[64];
#pragma unroll
  for (int m = 0; m < 64; ++m) wreg[m] = W2p[(64 * half + m) * GG + col];
#pragma unroll
  for (int m = 0; m < 64; ++m) asm volatile("" : "+v"(wreg[m]));

  float creg = 0.f, hlast = 0.f;
  if (!half) creg = c0[b * ESZ + j];

  const _Float16* preB = pre + (size_t)b * TT * GG;
  _Float16 q = (_Float16)0.f;
  if (!half) q = preB[col];      // only h0 carries pre

  for (int s = 0; s < TT; ++s) {
    // ---- poll own word (1 per lane): word 64*half + l, tag == s ----
    u64* basep = slab + (size_t)(s & 1) * (BB * NW) + b * NW + 64 * half;
    u64 wv_;
    do {
      wv_ = __hip_atomic_load(&basep[l], __ATOMIC_RELAXED, __HIP_MEMORY_SCOPE_AGENT);
    } while ((u32)wv_ != (u32)s);
    u32 hv_ = (u32)(wv_ >> 32);  // h2 row 64*half + l

    // ---- 64-row dot: uniform-src readlane + dot2, 2 chains ----
    float A0 = 0.f, A1 = 0.f;
#pragma unroll
    for (int k = 0; k < 32; ++k) {
      u32 hm0 = (u32)__builtin_amdgcn_readlane((int)hv_, 2 * k);
      u32 hm1 = (u32)__builtin_amdgcn_readlane((int)hv_, 2 * k + 1);
      A0 = fdot2u(hm0, wreg[2 * k], A0);
      A1 = fdot2u(hm1, wreg[2 * k + 1], A1);
    }
    float A = A0 + A1;

    float qf = 0.f;
    if (!half) {
      qf = (float)q;
      if (s + 1 < TT) q = preB[(size_t)(s + 1) * GG + col];  // prefetch
    } else {
      part[s & 1][w][l] = A;     // hand partial to the h0 partner wave
    }

    asm volatile("s_waitcnt lgkmcnt(0)" ::: "memory");
    __builtin_amdgcn_s_barrier();

    if (!half) {                 // wave-uniform branch: h1 waves skip entirely
      float v = A + qf + part[s & 1][w | 1][l];
      float gv = (gate == 3) ? tanh_f(v) : sigm_f(v);

      float fg = __shfl(gv, es_l);
      float ig = __shfl(gv, es_l + 16);
      float og = __shfl(gv, es_l + 32);
      float ch = __shfl(gv, es_l + 48);
      creg = fg * creg + ig * ch;
      float hv = og * tanh_f(creg);
      hlast = hv;

      // publish tagged word (es pair) into the other parity slot
      float hp = __shfl_xor(hv, 1);
      if (l < 16 && (l & 1) == 0) {
        _Float16 lo16 = (_Float16)hv, hi16 = (_Float16)hp;
        u32 h2p = (u32)__builtin_bit_cast(u16, lo16) | ((u32)__builtin_bit_cast(u16, hi16) << 16);
        u64 word = ((u64)h2p << 32) | (u32)(s + 1);
        int r = (E0 + l) >> 1;
        u64* outp = slab + (size_t)((s + 1) & 1) * (BB * NW) + b * NW + r;
        __hip_atomic_store(outp, word, __ATOMIC_RELAXED, __HIP_MEMORY_SCOPE_AGENT);
      }
      if (l < 16) {
        out1[(size_t)b * TT * ESZ + (size_t)s * ESZ + j] = hv;   // [B, T*es]
        out2[(size_t)s * (BB * ESZ) + b * ESZ + j] = hv;         // [T, B, es]
      }
    }
  }

  if (!half && l < 16) {
    hN[b * ESZ + j] = hlast;
    cN[b * ESZ + j] = creg;
  }
}

// ---------------- launch ----------------
extern "C" void kernel_launch(void* const* d_in, const int* in_sizes, int n_in,
                              void* d_out, int out_size, void* d_ws, size_t ws_size,
                              hipStream_t stream) {
  const float* x  = (const float*)d_in[0];
  const float* h0 = (const float*)d_in[1];
  const float* c0 = (const float*)d_in[2];
  const float* W1 = (const float*)d_in[3];
  const float* W2 = (const float*)d_in[4];
  const float* b1 = (const float*)d_in[5];
  const float* b2 = (const float*)d_in[6];

  float* out1 = (float*)d_out;
  float* out2 = out1 + (size_t)BB * TT * ESZ;
  float* hN   = out2 + (size_t)BB * TT * ESZ;
  float* cN   = hN + BB * ESZ;

  _Float16* pre = (_Float16*)d_ws;                                  // 128 MB
  u32* W2p = (u32*)((char*)d_ws + (size_t)BB * TT * GG * 2);        // 512 KB
  u64* slab = (u64*)((char*)W2p + 128 * GG * 4);                    // 64 KB

  k_pack_w2<<<512, 256, 0, stream>>>(W2, W2p);
  k_init_slab<<<32, 256, 0, stream>>>(h0, slab);
  k_pre_gemm<<<dim3(512, 16), 256, 0, stream>>>(x, W1, b1, b2, pre);

  k_lstm_rec<<<NG * BB, 256, 0, stream>>>(pre, W2p, c0, slab, out1, out2, hN, cN);
}